// Round 13
// baseline (82.571 us; speedup 1.0000x reference)
//
#include <hip/hip_runtime.h>
#include <math.h>

#define N_PRED   8192
#define N_CLS    150
#define N_BATCH  16
#define T_DIM    (N_BATCH * N_CLS)          // 2400
#define NPIX     (N_BATCH * 1024 * 1024)    // 16777216
#define PIX_SHIFT 20                         // pixels per image = 2^20

#define STRIPE   16384                       // pixels per partition block
#define NBLK_A   (NPIX / STRIPE)             // 1024 (stripes never cross images)
#define NBUK     512                         // p-buckets of 16 consecutive p
#define P_PER_BUK 16

#define KEYS_BYTES ((size_t)NPIX * 2)               // 33,554,432 (stripe-major)
#define DIRT_BYTES ((size_t)NBUK * NBLK_A * 4)      // 2,097,152  dirT[q][s]
#define NT_BYTES   ((size_t)T_DIM * 4)              // 9,600

// ---------------- Pass A: register-buffered counting sort, stripe-major keys ----------------
// 1024 thr, 16 px/thread in 16 VGPRs as w=(p<<12)|t. One global input read.
// Two-level shfl scan (2 barriers, was 9). Single s_nt (replicas proven useless, R10).
__global__ __launch_bounds__(1024, 8) void partition_kernel(
    const int* __restrict__ predseg, const int* __restrict__ targetseg,
    unsigned short* __restrict__ keys, unsigned* __restrict__ dirT,
    unsigned* __restrict__ g_nt) {
    __shared__ unsigned s_cnt[NBUK];            // counts -> run cursors
    __shared__ unsigned s_sa[NBUK];             // intra-wave inclusive scans
    __shared__ unsigned s_wsum[8];              // per-wave totals -> inclusive
    __shared__ unsigned s_nt[N_CLS];
    __shared__ unsigned short s_keys[STRIPE];   // 32KB

    int tid = threadIdx.x;
    int blk = blockIdx.x;
    size_t base = (size_t)blk * STRIPE;
    int tbase = (int)(base >> PIX_SHIFT) * N_CLS;   // image uniform per stripe

    if (tid < NBUK)  s_cnt[tid] = 0u;
    if (tid < N_CLS) s_nt[tid]  = 0u;
    __syncthreads();

    const int4* pv4 = (const int4*)(predseg   + base);
    const int4* cv4 = (const int4*)(targetseg + base);

    // phase 1: single global read -> 16 u32 regs; count buckets + classes
    unsigned kreg[16];
    #pragma unroll
    for (int i = 0; i < 4; ++i) {
        int idx = tid + i * 1024;
        int4 pv = pv4[idx]; int4 cv = cv4[idx];
        unsigned w0 = ((unsigned)pv.x << 12) | (unsigned)(tbase + cv.x);
        unsigned w1 = ((unsigned)pv.y << 12) | (unsigned)(tbase + cv.y);
        unsigned w2 = ((unsigned)pv.z << 12) | (unsigned)(tbase + cv.z);
        unsigned w3 = ((unsigned)pv.w << 12) | (unsigned)(tbase + cv.w);
        kreg[4 * i]     = w0; kreg[4 * i + 1] = w1;
        kreg[4 * i + 2] = w2; kreg[4 * i + 3] = w3;
        atomicAdd(&s_cnt[w0 >> 16], 1u); atomicAdd(&s_cnt[w1 >> 16], 1u);
        atomicAdd(&s_cnt[w2 >> 16], 1u); atomicAdd(&s_cnt[w3 >> 16], 1u);
        atomicAdd(&s_nt[cv.x], 1u); atomicAdd(&s_nt[cv.y], 1u);
        atomicAdd(&s_nt[cv.z], 1u); atomicAdd(&s_nt[cv.w], 1u);
    }
    __syncthreads();

    // two-level inclusive scan over 512 u32 (2 barriers)
    int lane = tid & 63;
    if (tid < NBUK) {
        unsigned x = s_cnt[tid];
        #pragma unroll
        for (int d = 1; d < 64; d <<= 1) {
            unsigned y = __shfl_up(x, d, 64);
            if (lane >= d) x += y;
        }
        if (lane == 63) s_wsum[tid >> 6] = x;   // wave total
        s_sa[tid] = x;                          // intra-wave inclusive
    }
    __syncthreads();
    if (tid < 8) {                              // scan 8 wave totals (width-8 groups)
        unsigned v = s_wsum[tid];
        #pragma unroll
        for (int d = 1; d < 8; d <<= 1) {
            unsigned y = __shfl_up(v, d, 8);
            if ((tid & 7) >= d) v += y;
        }
        s_wsum[tid] = v;                        // inclusive
    }
    __syncthreads();

    // transposed directory write + run cursors = exclusive offsets
    if (tid < NBUK) {
        unsigned wofs = (tid >= 64) ? s_wsum[(tid >> 6) - 1] : 0u;
        unsigned incl = s_sa[tid] + wofs;
        unsigned cnt  = s_cnt[tid];
        unsigned excl = incl - cnt;
        dirT[(size_t)tid * NBLK_A + blk] = excl | (cnt << 16);
        s_cnt[tid] = excl;                      // becomes the running cursor
    }
    __syncthreads();

    // phase 2: scatter keys from registers into LDS grouped by bucket (no VMEM)
    #pragma unroll
    for (int i = 0; i < 16; ++i) {
        unsigned w = kreg[i];
        unsigned slot = atomicAdd(&s_cnt[w >> 16], 1u);
        s_keys[slot] = (unsigned short)w;
    }
    __syncthreads();

    // phase 3: whole-stripe coalesced 32KB store (stripe-major layout)
    uint4* dstv = (uint4*)(keys + base);
    const uint4* srcv = (const uint4*)s_keys;
    #pragma unroll
    for (int i = 0; i < 2; ++i) dstv[tid + i * 1024] = srcv[tid + i * 1024];

    // deferred n_t flush (overlaps the store drain)
    if (tid < N_CLS) {
        unsigned v = s_nt[tid];
        if (v) atomicAdd(&g_nt[tbase + tid], v);
    }
}

// ---------------- Pass B: per-bucket histogram + FUSED sweep/softmax/focal loss ----------------
// Block q owns rows p = q*16..q*16+15 entirely -> compute the per-row loss here.
// LDS: hist u8 38.4KB + dir 4KB + nt_f 9.6KB = 52.1KB -> 2 blocks/CU = 100% occ.
__global__ __launch_bounds__(1024, 8) void hist_loss_kernel(
    const unsigned short* __restrict__ keys, const unsigned* __restrict__ dirT,
    const unsigned* __restrict__ g_nt, const float* __restrict__ pred,
    float* __restrict__ loss_out, float cnorm) {
    __shared__ unsigned s_hist[P_PER_BUK * T_DIM / 4];   // 9600 words, u8-packed
    __shared__ unsigned s_dir[NBLK_A];                   // 4KB
    __shared__ float s_ntf[T_DIM];                       // 9.6KB
    __shared__ float s_loss[P_PER_BUK];

    int tid = threadIdx.x;
    int q   = blockIdx.x;
    for (int i = tid; i < P_PER_BUK * T_DIM / 4; i += 1024) s_hist[i] = 0u;
    s_dir[tid] = dirT[(size_t)q * NBLK_A + tid];         // NBLK_A == 1024 == blockDim
    for (int i = tid; i < T_DIM; i += 1024) s_ntf[i] = (float)g_nt[i];
    __syncthreads();

    int wid  = tid >> 6;          // 0..15
    int lane = tid & 63;
    int g    = lane >> 4;         // subgroup 0..3
    int u    = lane & 15;

    // histogram: 64 segment slots (16 waves x 4 subgroups); aligned u32 = 2 keys
    for (int s = wid * 4 + g; s < NBLK_A; s += 64) {
        unsigned d = s_dir[s];
        int start = (int)(d & 0xFFFFu);
        int cnt   = (int)(d >> 16);
        if (!cnt) continue;
        int end = start + cnt;
        const unsigned* kw = (const unsigned*)(keys + (size_t)s * STRIPE);
        int w0 = start >> 1;
        int w1 = (end - 1) >> 1;
        for (int w = w0 + u; w <= w1; w += 16) {
            unsigned x = kw[w];
            if (2 * w >= start) {
                unsigned k = x & 0xFFFFu;
                unsigned bin = (k >> 12) * T_DIM + (k & 4095u);
                atomicAdd(&s_hist[bin >> 2], 1u << ((bin & 3u) * 8));
            }
            if (2 * w + 1 < end) {
                unsigned k = x >> 16;
                unsigned bin = (k >> 12) * T_DIM + (k & 4095u);
                atomicAdd(&s_hist[bin >> 2], 1u << ((bin & 3u) * 8));
            }
        }
    }
    __syncthreads();

    // ---- fused epilogue: wave `wid` handles output row p = q*16 + wid ----
    float np;
    {
        unsigned sum = 0;
        const unsigned* row = s_hist + wid * (T_DIM / 4);
        for (int t = lane; t < T_DIM / 4; t += 64) {
            unsigned w = row[t];
            sum += (w & 0xFFu) + ((w >> 8) & 0xFFu) + ((w >> 16) & 0xFFu) + (w >> 24);
        }
        #pragma unroll
        for (int off = 32; off; off >>= 1) sum += __shfl_xor(sum, off);
        np = (float)sum;
    }

    const float* pr = pred + (size_t)(q * P_PER_BUK + wid) * N_CLS;
    float pv[3], ov[3];
    float rowsum = 0.f, pmax = -INFINITY;
    #pragma unroll
    for (int k = 0; k < 3; ++k) {
        int c = lane + k * 64;
        bool ok = c < N_CLS;
        pv[k] = ok ? pr[c] : -INFINITY;
        float acc = 0.f;
        if (ok) {
            #pragma unroll
            for (int b = 0; b < N_BATCH; ++b) {
                int t = b * N_CLS + c;
                unsigned bin = (unsigned)(wid * T_DIM + t);
                unsigned cb = (s_hist[bin >> 2] >> ((bin & 3u) * 8)) & 0xFFu;
                if (cb) {
                    float f = (float)cb;
                    acc += f / (np + s_ntf[t] - f);
                }
            }
        }
        ov[k] = acc;
        rowsum += acc;
        pmax = fmaxf(pmax, pv[k]);
    }
    #pragma unroll
    for (int off = 32; off; off >>= 1) {
        rowsum += __shfl_xor(rowsum, off);
        pmax = fmaxf(pmax, __shfl_xor(pmax, off));
    }
    float sumexp = 0.f;
    #pragma unroll
    for (int k = 0; k < 3; ++k) {
        int c = lane + k * 64;
        if (c < N_CLS) sumexp += __expf(pv[k] - pmax);
    }
    #pragma unroll
    for (int off = 32; off; off >>= 1) sumexp += __shfl_xor(sumexp, off);
    float lse = __logf(sumexp) + pmax;      // logp[c] = pred[c] - lse

    float inv = 1.f / rowsum;
    float ce = 0.f, bestv = -INFINITY;
    int besti = 0;
    #pragma unroll
    for (int k = 0; k < 3; ++k) {
        int c = lane + k * 64;
        if (c >= N_CLS) continue;
        float tg = ov[k] * inv;
        if (c != 0) ce -= tg * (pv[k] - lse);   // cls_w[0] = 0
        if (tg > bestv) { bestv = tg; besti = c; }  // first max within lane
    }
    #pragma unroll
    for (int off = 32; off; off >>= 1) {
        ce += __shfl_xor(ce, off);
        float bv = __shfl_xor(bestv, off);
        int   bi = __shfl_xor(besti, off);
        if (bv > bestv || (bv == bestv && bi < besti)) { bestv = bv; besti = bi; }
    }
    if (lane == 0) {
        float ptv = __expf(pr[besti] - lse);    // softmax at argmax(target)
        float x  = 1.f - ptv;
        float x2 = x * x;
        s_loss[wid] = x2 * x2 * ce * cnorm;
    }
    __syncthreads();
    if (tid == 0) {
        float s = 0.f;
        #pragma unroll
        for (int r = 0; r < P_PER_BUK; ++r) s += s_loss[r];
        atomicAdd(loss_out, s * (1.0f / (float)N_PRED));
    }
}

// Host-side: reproduce _norm_factor(4.0) — trapezoid of (1-t^5)/(1-t), 1000 pts.
static float compute_cnorm() {
    const double eps = 1e-7, gamma = 4.0;
    double h = 0.0, prev_t = 0.0, prev_y = 1.0;   // y(0) = 1
    for (int i = 1; i < 1000; ++i) {
        double t = (double)i * (1.0 - eps) / 999.0;
        double y = (1.0 - pow(t, gamma + 1.0)) / (1.0 - t);
        h += 0.5 * (y + prev_y) * (t - prev_t);
        prev_t = t; prev_y = y;
    }
    return (float)((gamma + 1.0) / h);
}

extern "C" void kernel_launch(void* const* d_in, const int* in_sizes, int n_in,
                              void* d_out, int out_size, void* d_ws, size_t ws_size,
                              hipStream_t stream) {
    const float* pred      = (const float*)d_in[0];
    const int*   predseg   = (const int*)d_in[1];
    const int*   targetseg = (const int*)d_in[2];

    unsigned char* ws = (unsigned char*)d_ws;
    unsigned short* keys = (unsigned short*)ws;
    unsigned* dirT = (unsigned*)(ws + KEYS_BYTES);
    unsigned* g_nt = (unsigned*)(ws + KEYS_BYTES + DIRT_BYTES);

    float cnorm = compute_cnorm();

    hipMemsetAsync(g_nt, 0, NT_BYTES, stream);
    hipMemsetAsync(d_out, 0, sizeof(float) * (size_t)out_size, stream);

    partition_kernel<<<NBLK_A, 1024, 0, stream>>>(predseg, targetseg, keys, dirT, g_nt);
    hist_loss_kernel<<<NBUK,   1024, 0, stream>>>(keys, dirT, g_nt, pred,
                                                  (float*)d_out, cnorm);
}

// Round 14
// 82.075 us; speedup vs baseline: 1.0060x; 1.0060x over previous
//
#include <hip/hip_runtime.h>
#include <math.h>

#define N_PRED   8192
#define N_CLS    150
#define N_BATCH  16
#define T_DIM    (N_BATCH * N_CLS)          // 2400
#define NPIX     (N_BATCH * 1024 * 1024)    // 16777216
#define PIX_SHIFT 20                         // pixels per image = 2^20

#define STRIPE   16384                       // pixels per partition block
#define NBLK_A   (NPIX / STRIPE)             // 1024 (stripes never cross images)
#define NBUK     512                         // p-buckets of 16 consecutive p
#define P_PER_BUK 16

#define KEYS_BYTES ((size_t)NPIX * 2)               // 33,554,432 (stripe-major)
#define DIRT_BYTES ((size_t)NBUK * NBLK_A * 4)      // 2,097,152  dirT[q][s]
#define NT_BYTES   ((size_t)T_DIM * 4)              // 9,600

// ---------------- Pass A: register-buffered counting sort, stripe-major keys ----------------
// 1024 thr, 16 px/thread in 16 VGPRs as w=(p<<12)|t. One global input read.
// Two-level shfl scan (2 barriers, was 9). Single s_nt (replicas proven useless, R10).
__global__ __launch_bounds__(1024, 8) void partition_kernel(
    const int* __restrict__ predseg, const int* __restrict__ targetseg,
    unsigned short* __restrict__ keys, unsigned* __restrict__ dirT,
    unsigned* __restrict__ g_nt) {
    __shared__ unsigned s_cnt[NBUK];            // counts -> run cursors
    __shared__ unsigned s_sa[NBUK];             // intra-wave inclusive scans
    __shared__ unsigned s_wsum[8];              // per-wave totals -> inclusive
    __shared__ unsigned s_nt[N_CLS];
    __shared__ unsigned short s_keys[STRIPE];   // 32KB

    int tid = threadIdx.x;
    int blk = blockIdx.x;
    size_t base = (size_t)blk * STRIPE;
    int tbase = (int)(base >> PIX_SHIFT) * N_CLS;   // image uniform per stripe

    if (tid < NBUK)  s_cnt[tid] = 0u;
    if (tid < N_CLS) s_nt[tid]  = 0u;
    __syncthreads();

    const int4* pv4 = (const int4*)(predseg   + base);
    const int4* cv4 = (const int4*)(targetseg + base);

    // phase 1: single global read -> 16 u32 regs; count buckets + classes
    unsigned kreg[16];
    #pragma unroll
    for (int i = 0; i < 4; ++i) {
        int idx = tid + i * 1024;
        int4 pv = pv4[idx]; int4 cv = cv4[idx];
        unsigned w0 = ((unsigned)pv.x << 12) | (unsigned)(tbase + cv.x);
        unsigned w1 = ((unsigned)pv.y << 12) | (unsigned)(tbase + cv.y);
        unsigned w2 = ((unsigned)pv.z << 12) | (unsigned)(tbase + cv.z);
        unsigned w3 = ((unsigned)pv.w << 12) | (unsigned)(tbase + cv.w);
        kreg[4 * i]     = w0; kreg[4 * i + 1] = w1;
        kreg[4 * i + 2] = w2; kreg[4 * i + 3] = w3;
        atomicAdd(&s_cnt[w0 >> 16], 1u); atomicAdd(&s_cnt[w1 >> 16], 1u);
        atomicAdd(&s_cnt[w2 >> 16], 1u); atomicAdd(&s_cnt[w3 >> 16], 1u);
        atomicAdd(&s_nt[cv.x], 1u); atomicAdd(&s_nt[cv.y], 1u);
        atomicAdd(&s_nt[cv.z], 1u); atomicAdd(&s_nt[cv.w], 1u);
    }
    __syncthreads();

    // two-level inclusive scan over 512 u32 (2 barriers)
    int lane = tid & 63;
    if (tid < NBUK) {
        unsigned x = s_cnt[tid];
        #pragma unroll
        for (int d = 1; d < 64; d <<= 1) {
            unsigned y = __shfl_up(x, d, 64);
            if (lane >= d) x += y;
        }
        if (lane == 63) s_wsum[tid >> 6] = x;   // wave total
        s_sa[tid] = x;                          // intra-wave inclusive
    }
    __syncthreads();
    if (tid < 8) {                              // scan 8 wave totals (width-8 groups)
        unsigned v = s_wsum[tid];
        #pragma unroll
        for (int d = 1; d < 8; d <<= 1) {
            unsigned y = __shfl_up(v, d, 8);
            if ((tid & 7) >= d) v += y;
        }
        s_wsum[tid] = v;                        // inclusive
    }
    __syncthreads();

    // transposed directory write + run cursors = exclusive offsets
    if (tid < NBUK) {
        unsigned wofs = (tid >= 64) ? s_wsum[(tid >> 6) - 1] : 0u;
        unsigned incl = s_sa[tid] + wofs;
        unsigned cnt  = s_cnt[tid];
        unsigned excl = incl - cnt;
        dirT[(size_t)tid * NBLK_A + blk] = excl | (cnt << 16);
        s_cnt[tid] = excl;                      // becomes the running cursor
    }
    __syncthreads();

    // phase 2: scatter keys from registers into LDS grouped by bucket (no VMEM)
    #pragma unroll
    for (int i = 0; i < 16; ++i) {
        unsigned w = kreg[i];
        unsigned slot = atomicAdd(&s_cnt[w >> 16], 1u);
        s_keys[slot] = (unsigned short)w;
    }
    __syncthreads();

    // phase 3: whole-stripe coalesced 32KB store (stripe-major layout)
    uint4* dstv = (uint4*)(keys + base);
    const uint4* srcv = (const uint4*)s_keys;
    #pragma unroll
    for (int i = 0; i < 2; ++i) dstv[tid + i * 1024] = srcv[tid + i * 1024];

    // deferred n_t flush (overlaps the store drain)
    if (tid < N_CLS) {
        unsigned v = s_nt[tid];
        if (v) atomicAdd(&g_nt[tbase + tid], v);
    }
}

// ---------------- Pass B: per-bucket histogram + FUSED sweep/softmax/focal loss ----------------
// Block q owns rows p = q*16..q*16+15 entirely -> compute the per-row loss here.
// LDS: hist u8 38.4KB + dir 4KB + nt_f 9.6KB = 52.1KB -> 2 blocks/CU = 100% occ.
__global__ __launch_bounds__(1024, 8) void hist_loss_kernel(
    const unsigned short* __restrict__ keys, const unsigned* __restrict__ dirT,
    const unsigned* __restrict__ g_nt, const float* __restrict__ pred,
    float* __restrict__ loss_out, float cnorm) {
    __shared__ unsigned s_hist[P_PER_BUK * T_DIM / 4];   // 9600 words, u8-packed
    __shared__ unsigned s_dir[NBLK_A];                   // 4KB
    __shared__ float s_ntf[T_DIM];                       // 9.6KB
    __shared__ float s_loss[P_PER_BUK];

    int tid = threadIdx.x;
    int q   = blockIdx.x;
    for (int i = tid; i < P_PER_BUK * T_DIM / 4; i += 1024) s_hist[i] = 0u;
    s_dir[tid] = dirT[(size_t)q * NBLK_A + tid];         // NBLK_A == 1024 == blockDim
    for (int i = tid; i < T_DIM; i += 1024) s_ntf[i] = (float)g_nt[i];
    __syncthreads();

    int wid  = tid >> 6;          // 0..15
    int lane = tid & 63;
    int g    = lane >> 4;         // subgroup 0..3
    int u    = lane & 15;

    // histogram: 64 segment slots (16 waves x 4 subgroups); aligned u32 = 2 keys
    for (int s = wid * 4 + g; s < NBLK_A; s += 64) {
        unsigned d = s_dir[s];
        int start = (int)(d & 0xFFFFu);
        int cnt   = (int)(d >> 16);
        if (!cnt) continue;
        int end = start + cnt;
        const unsigned* kw = (const unsigned*)(keys + (size_t)s * STRIPE);
        int w0 = start >> 1;
        int w1 = (end - 1) >> 1;
        for (int w = w0 + u; w <= w1; w += 16) {
            unsigned x = kw[w];
            if (2 * w >= start) {
                unsigned k = x & 0xFFFFu;
                unsigned bin = (k >> 12) * T_DIM + (k & 4095u);
                atomicAdd(&s_hist[bin >> 2], 1u << ((bin & 3u) * 8));
            }
            if (2 * w + 1 < end) {
                unsigned k = x >> 16;
                unsigned bin = (k >> 12) * T_DIM + (k & 4095u);
                atomicAdd(&s_hist[bin >> 2], 1u << ((bin & 3u) * 8));
            }
        }
    }
    __syncthreads();

    // ---- fused epilogue: wave `wid` handles output row p = q*16 + wid ----
    float np;
    {
        unsigned sum = 0;
        const unsigned* row = s_hist + wid * (T_DIM / 4);
        for (int t = lane; t < T_DIM / 4; t += 64) {
            unsigned w = row[t];
            sum += (w & 0xFFu) + ((w >> 8) & 0xFFu) + ((w >> 16) & 0xFFu) + (w >> 24);
        }
        #pragma unroll
        for (int off = 32; off; off >>= 1) sum += __shfl_xor(sum, off);
        np = (float)sum;
    }

    const float* pr = pred + (size_t)(q * P_PER_BUK + wid) * N_CLS;
    float pv[3], ov[3];
    float rowsum = 0.f, pmax = -INFINITY;
    #pragma unroll
    for (int k = 0; k < 3; ++k) {
        int c = lane + k * 64;
        bool ok = c < N_CLS;
        pv[k] = ok ? pr[c] : -INFINITY;
        float acc = 0.f;
        if (ok) {
            #pragma unroll
            for (int b = 0; b < N_BATCH; ++b) {
                int t = b * N_CLS + c;
                unsigned bin = (unsigned)(wid * T_DIM + t);
                unsigned cb = (s_hist[bin >> 2] >> ((bin & 3u) * 8)) & 0xFFu;
                if (cb) {
                    float f = (float)cb;
                    acc += f / (np + s_ntf[t] - f);
                }
            }
        }
        ov[k] = acc;
        rowsum += acc;
        pmax = fmaxf(pmax, pv[k]);
    }
    #pragma unroll
    for (int off = 32; off; off >>= 1) {
        rowsum += __shfl_xor(rowsum, off);
        pmax = fmaxf(pmax, __shfl_xor(pmax, off));
    }
    float sumexp = 0.f;
    #pragma unroll
    for (int k = 0; k < 3; ++k) {
        int c = lane + k * 64;
        if (c < N_CLS) sumexp += __expf(pv[k] - pmax);
    }
    #pragma unroll
    for (int off = 32; off; off >>= 1) sumexp += __shfl_xor(sumexp, off);
    float lse = __logf(sumexp) + pmax;      // logp[c] = pred[c] - lse

    float inv = 1.f / rowsum;
    float ce = 0.f, bestv = -INFINITY;
    int besti = 0;
    #pragma unroll
    for (int k = 0; k < 3; ++k) {
        int c = lane + k * 64;
        if (c >= N_CLS) continue;
        float tg = ov[k] * inv;
        if (c != 0) ce -= tg * (pv[k] - lse);   // cls_w[0] = 0
        if (tg > bestv) { bestv = tg; besti = c; }  // first max within lane
    }
    #pragma unroll
    for (int off = 32; off; off >>= 1) {
        ce += __shfl_xor(ce, off);
        float bv = __shfl_xor(bestv, off);
        int   bi = __shfl_xor(besti, off);
        if (bv > bestv || (bv == bestv && bi < besti)) { bestv = bv; besti = bi; }
    }
    if (lane == 0) {
        float ptv = __expf(pr[besti] - lse);    // softmax at argmax(target)
        float x  = 1.f - ptv;
        float x2 = x * x;
        s_loss[wid] = x2 * x2 * ce * cnorm;
    }
    __syncthreads();
    if (tid == 0) {
        float s = 0.f;
        #pragma unroll
        for (int r = 0; r < P_PER_BUK; ++r) s += s_loss[r];
        atomicAdd(loss_out, s * (1.0f / (float)N_PRED));
    }
}

// Host-side: reproduce _norm_factor(4.0) — trapezoid of (1-t^5)/(1-t), 1000 pts.
static float compute_cnorm() {
    const double eps = 1e-7, gamma = 4.0;
    double h = 0.0, prev_t = 0.0, prev_y = 1.0;   // y(0) = 1
    for (int i = 1; i < 1000; ++i) {
        double t = (double)i * (1.0 - eps) / 999.0;
        double y = (1.0 - pow(t, gamma + 1.0)) / (1.0 - t);
        h += 0.5 * (y + prev_y) * (t - prev_t);
        prev_t = t; prev_y = y;
    }
    return (float)((gamma + 1.0) / h);
}

extern "C" void kernel_launch(void* const* d_in, const int* in_sizes, int n_in,
                              void* d_out, int out_size, void* d_ws, size_t ws_size,
                              hipStream_t stream) {
    const float* pred      = (const float*)d_in[0];
    const int*   predseg   = (const int*)d_in[1];
    const int*   targetseg = (const int*)d_in[2];

    unsigned char* ws = (unsigned char*)d_ws;
    unsigned short* keys = (unsigned short*)ws;
    unsigned* dirT = (unsigned*)(ws + KEYS_BYTES);
    unsigned* g_nt = (unsigned*)(ws + KEYS_BYTES + DIRT_BYTES);

    float cnorm = compute_cnorm();

    hipMemsetAsync(g_nt, 0, NT_BYTES, stream);
    hipMemsetAsync(d_out, 0, sizeof(float) * (size_t)out_size, stream);

    partition_kernel<<<NBLK_A, 1024, 0, stream>>>(predseg, targetseg, keys, dirT, g_nt);
    hist_loss_kernel<<<NBUK,   1024, 0, stream>>>(keys, dirT, g_nt, pred,
                                                  (float*)d_out, cnorm);
}